// Round 6
// baseline (106.643 us; speedup 1.0000x reference)
//
#include <hip/hip_runtime.h>
#include <hip/hip_bf16.h>

#define N0 65536
#define N1 16384
#define K0 32
#define N2 150
#define K1 64
#define BB 64   // batch == wavefront size

// ws layout: xT bf16 (8 MiB) | h0T bf16 (2 MiB) | used (16 KiB)
// xT/h0T layout: [neuron][batch] bf16, batch fastest. Viewed as uint*, word
// bp holds batches (2bp, 2bp+1) (little-endian: low half = even batch).
// Packed-gather scheme: lanes 0-31 fetch column for k-even (batch-pair bp =
// lane&31), lanes 32-63 fetch k-odd -> one 256B wave-gather serves two k's;
// halves combine via __shfl_xor(acc, 32). fp32 accumulation throughout.
// `used` poison-safety: k_transpose rewrites used[conn1[*]]=1 every call
// BEFORE k_layer0 reads it (stream order); 0xAA != 1 so stale bytes only
// skip genuinely-unused neurons.

__device__ __forceinline__ float bf16lo(unsigned int v) {
    return __uint_as_float(v << 16);
}
__device__ __forceinline__ float bf16hi(unsigned int v) {
    return __uint_as_float(v & 0xffff0000u);
}
__device__ __forceinline__ unsigned int pack_bf16(float lo, float hi) {
    unsigned int l = __bfloat16_as_ushort(__float2bfloat16(lo));
    unsigned int h = __bfloat16_as_ushort(__float2bfloat16(hi));
    return (h << 16) | l;
}

// ---------------------------------------------------------------------------
// Kernel 1: transpose x (64 x 65536) f32 -> xT (65536 x 64) bf16;
// mark used layer-0 neurons; bias-init out.
// ---------------------------------------------------------------------------
__global__ __launch_bounds__(256) void k_transpose(const float* __restrict__ x,
                                                   const int* __restrict__ conn1,
                                                   const float* __restrict__ fc_b,
                                                   float* __restrict__ out,
                                                   __hip_bfloat16* __restrict__ xT,
                                                   unsigned char* __restrict__ used) {
    __shared__ float tile[64][65];
    const int c0 = blockIdx.x << 6;
    const int t  = threadIdx.x;
    if (blockIdx.x == 0 && t < BB * 2) out[t] = fc_b[t & 1];
    const int rr = t >> 4;           // 0..15
    const int c4 = (t & 15) << 2;    // 0,4,...,60
#pragma unroll
    for (int i = 0; i < 4; ++i) {
        const int row = (i << 4) + rr;
        const float4 v = *(const float4*)(x + (size_t)row * N0 + c0 + c4);
        tile[row][c4 + 0] = v.x;
        tile[row][c4 + 1] = v.y;
        tile[row][c4 + 2] = v.z;
        tile[row][c4 + 3] = v.w;
    }
    __syncthreads();
    const int cc = t & 63;
    const int r4 = t >> 6;
#pragma unroll
    for (int i = 0; i < 16; ++i) {
        const int c = (r4 << 4) + i;
        xT[(size_t)(c0 + c) * BB + cc] = __float2bfloat16(tile[cc][c]);
    }
    const int g = (blockIdx.x << 8) + t;             // covers [0, 262144)
    if (g < N2 * K1) used[conn1[g]] = 1;
}

// ---------------------------------------------------------------------------
// Kernel 2: layer 0, gated by `used`. One wave per neuron; two k's per
// gather instruction; 16 fully-unrolled gathers = one latency batch.
// ---------------------------------------------------------------------------
__global__ __launch_bounds__(256, 8) void k_layer0(const __hip_bfloat16* __restrict__ xT,
                                                   const int*   __restrict__ conn0,
                                                   const float* __restrict__ W0,
                                                   const float* __restrict__ b0,
                                                   const unsigned char* __restrict__ used,
                                                   __hip_bfloat16* __restrict__ h0T) {
    const int lane = threadIdx.x & 63;
    const int n = __builtin_amdgcn_readfirstlane((blockIdx.x << 2) + (threadIdx.x >> 6));
    if (used[n] != 1) return;                        // wave-uniform skip
    const int*   __restrict__ cp = conn0 + (n << 5);
    const float* __restrict__ wp = W0 + (n << 5);
    const unsigned int* __restrict__ xT2 = (const unsigned int*)xT;
    const int bp = lane & 31;                        // batch-pair index
    const int kh = lane >> 5;                        // 0: even k, 1: odd k
    float accL = 0.f, accH = 0.f;
#pragma unroll
    for (int k2 = 0; k2 < 16; ++k2) {
        const int   ce = cp[(k2 << 1) + 0], co = cp[(k2 << 1) + 1];  // s_load
        const float we = wp[(k2 << 1) + 0], wo = wp[(k2 << 1) + 1];  // s_load
        const int   c = kh ? co : ce;
        const float w = kh ? wo : we;
        const unsigned int v = xT2[((size_t)c << 5) + bp];           // 256B/wave
        accL = fmaf(bf16lo(v), w, accL);
        accH = fmaf(bf16hi(v), w, accH);
    }
    accL += __shfl_xor(accL, 32);                    // fold odd-k half
    accH += __shfl_xor(accH, 32);
    if (kh == 0) {
        const float bn = b0[n];
        ((unsigned int*)h0T)[(n << 5) + bp] =
            pack_bf16(fmaxf(accL + bn, 0.f), fmaxf(accH + bn, 0.f));
    }
}

// ---------------------------------------------------------------------------
// Kernel 3: layer 1 + FC head fused, same packed-gather scheme (64 -> 32
// gather instrs per neuron, fully unrolled).
// ---------------------------------------------------------------------------
__global__ __launch_bounds__(256) void k_layer1fc(const __hip_bfloat16* __restrict__ h0T,
                                                  const int*   __restrict__ conn1,
                                                  const float* __restrict__ W1,
                                                  const float* __restrict__ b1,
                                                  const float* __restrict__ fc_w,
                                                  float* __restrict__ out) {
    const int lane = threadIdx.x & 63;
    const int n = __builtin_amdgcn_readfirstlane((blockIdx.x << 2) + (threadIdx.x >> 6));
    if (n >= N2) return;
    const int*   __restrict__ cp = conn1 + (n << 6);
    const float* __restrict__ wp = W1 + (n << 6);
    const unsigned int* __restrict__ h0T2 = (const unsigned int*)h0T;
    const int bp = lane & 31;
    const int kh = lane >> 5;
    float accL = 0.f, accH = 0.f;
#pragma unroll
    for (int k2 = 0; k2 < 32; ++k2) {
        const int   ce = cp[(k2 << 1) + 0], co = cp[(k2 << 1) + 1];
        const float we = wp[(k2 << 1) + 0], wo = wp[(k2 << 1) + 1];
        const int   c = kh ? co : ce;
        const float w = kh ? wo : we;
        const unsigned int v = h0T2[((size_t)c << 5) + bp];
        accL = fmaf(bf16lo(v), w, accL);
        accH = fmaf(bf16hi(v), w, accH);
    }
    accL += __shfl_xor(accL, 32);
    accH += __shfl_xor(accH, 32);
    if (kh == 0) {
        const float bn = b1[n];
        const float h1L = fmaxf(accL + bn, 0.f);     // batch 2bp
        const float h1H = fmaxf(accH + bn, 0.f);     // batch 2bp+1
        const float w0 = fc_w[n];                    // fc_w[0][n]
        const float w1 = fc_w[N2 + n];               // fc_w[1][n]
        atomicAdd(&out[((bp << 1) + 0) * 2 + 0], h1L * w0);
        atomicAdd(&out[((bp << 1) + 0) * 2 + 1], h1L * w1);
        atomicAdd(&out[((bp << 1) + 1) * 2 + 0], h1H * w0);
        atomicAdd(&out[((bp << 1) + 1) * 2 + 1], h1H * w1);
    }
}

extern "C" void kernel_launch(void* const* d_in, const int* in_sizes, int n_in,
                              void* d_out, int out_size, void* d_ws, size_t ws_size,
                              hipStream_t stream) {
    const float* x     = (const float*)d_in[0];
    const int*   conn0 = (const int*)  d_in[1];
    const int*   conn1 = (const int*)  d_in[2];
    const float* W0    = (const float*)d_in[3];
    const float* b0    = (const float*)d_in[4];
    const float* W1    = (const float*)d_in[5];
    const float* b1    = (const float*)d_in[6];
    const float* fc_w  = (const float*)d_in[7];
    const float* fc_b  = (const float*)d_in[8];
    float* out = (float*)d_out;

    char* ws = (char*)d_ws;
    __hip_bfloat16* xT  = (__hip_bfloat16*)(ws);
    __hip_bfloat16* h0T = (__hip_bfloat16*)(ws + (size_t)N0 * BB * 2);
    unsigned char* used = (unsigned char*)(ws + (size_t)N0 * BB * 2
                                              + (size_t)N1 * BB * 2);

    k_transpose<<<N0 / 64, 256, 0, stream>>>(x, conn1, fc_b, out, xT, used);
    k_layer0<<<N1 / 4, 256, 0, stream>>>(xT, conn0, W0, b0, used, h0T);
    k_layer1fc<<<(N2 + 3) / 4, 256, 0, stream>>>(h0T, conn1, W1, b1, fc_w, out);
}

// Round 7
// 97.735 us; speedup vs baseline: 1.0912x; 1.0912x over previous
//
#include <hip/hip_runtime.h>
#include <hip/hip_bf16.h>

#define N0 65536
#define N1 16384
#define K0 32
#define N2 150
#define K1 64
#define BB 64   // batch == wavefront size

// ws layout: xT bf16 (8 MiB) | h0T bf16 (2 MiB) | used (16 KiB)
// xT/h0T: [neuron][batch] bf16, batch fastest; word bp = batches (2bp,2bp+1),
// little-endian low half = even batch.
// Gathers keep WAVE-UNIFORM columns (conn via s_load) -> global_load saddr,
// one 128B segment per instr (R6's packed variant regressed: 2 segments +
// vector addressing).
// `used` poison-safety: k_transpose rewrites used[conn1[*]]=1 every call
// BEFORE k_layer0 reads it (stream order); 0xAA != 1.
// `out` bias-init by k_transpose block 0; k_layer1fc atomicAdds on top.

__device__ __forceinline__ unsigned int pack_bf16(float lo, float hi) {
    unsigned int l = __bfloat16_as_ushort(__float2bfloat16(lo));
    unsigned int h = __bfloat16_as_ushort(__float2bfloat16(hi));
    return (h << 16) | l;
}

// ---------------------------------------------------------------------------
// Kernel 1: transpose x (64 x 65536) f32 -> xT (65536 x 64) bf16.
// Read: float4 coalesced. Write: uint (2 batches) per lane, wave halves
// cover adjacent columns -> one 256B contiguous store per 2 columns.
// ---------------------------------------------------------------------------
__global__ __launch_bounds__(256) void k_transpose(const float* __restrict__ x,
                                                   const int* __restrict__ conn1,
                                                   const float* __restrict__ fc_b,
                                                   float* __restrict__ out,
                                                   __hip_bfloat16* __restrict__ xT,
                                                   unsigned char* __restrict__ used) {
    __shared__ float tile[64][65];
    const int c0 = blockIdx.x << 6;
    const int t  = threadIdx.x;
    if (blockIdx.x == 0 && t < BB * 2) out[t] = fc_b[t & 1];
    const int rr = t >> 4;           // 0..15
    const int c4 = (t & 15) << 2;    // 0,4,...,60
#pragma unroll
    for (int i = 0; i < 4; ++i) {
        const int row = (i << 4) + rr;
        const float4 v = *(const float4*)(x + (size_t)row * N0 + c0 + c4);
        tile[row][c4 + 0] = v.x;
        tile[row][c4 + 1] = v.y;
        tile[row][c4 + 2] = v.z;
        tile[row][c4 + 3] = v.w;
    }
    __syncthreads();
    unsigned int* __restrict__ xT2 = (unsigned int*)xT;
    const int bp   = t & 31;         // batch-pair 0..31
    const int half = (t >> 5) & 1;   // column parity within the pair
    const int cq   = t >> 6;         // wave id -> 16-column group
#pragma unroll
    for (int i = 0; i < 8; ++i) {
        const int c = (cq << 4) + (i << 1) + half;
        xT2[((size_t)(c0 + c) << 5) + bp] =
            pack_bf16(tile[(bp << 1) + 0][c], tile[(bp << 1) + 1][c]);
    }
    const int g = (blockIdx.x << 8) + t;             // covers [0, 262144)
    if (g < N2 * K1) used[conn1[g]] = 1;
}

// ---------------------------------------------------------------------------
// Kernel 2: layer 0, gated by `used` (R5-proven form). One wave per neuron,
// wave-uniform column per gather, unroll 16, 8 blocks/CU.
// ---------------------------------------------------------------------------
__global__ __launch_bounds__(256, 8) void k_layer0(const __hip_bfloat16* __restrict__ xT,
                                                   const int*   __restrict__ conn0,
                                                   const float* __restrict__ W0,
                                                   const float* __restrict__ b0,
                                                   const unsigned char* __restrict__ used,
                                                   __hip_bfloat16* __restrict__ h0T) {
    const int lane = threadIdx.x & 63;
    const int n = __builtin_amdgcn_readfirstlane((blockIdx.x << 2) + (threadIdx.x >> 6));
    if (used[n] != 1) return;                        // wave-uniform skip
    const int*   __restrict__ cp = conn0 + (n << 5);
    const float* __restrict__ wp = W0 + (n << 5);
    float acc = 0.f;
#pragma unroll 16
    for (int k = 0; k < K0; ++k) {
        acc = fmaf(__bfloat162float(xT[((size_t)cp[k] << 6) + lane]), wp[k], acc);
    }
    acc += b0[n];
    h0T[(n << 6) + lane] = __float2bfloat16(fmaxf(acc, 0.f));
}

// ---------------------------------------------------------------------------
// Kernel 3: layer 1 + FC. One BLOCK per neuron: 4 waves x 16 k's, LDS
// partial reduce, wave 0 applies bias+relu and atomicAdds the FC head.
// Critical path: 16 gathers (one latency batch) instead of 64.
// ---------------------------------------------------------------------------
__global__ __launch_bounds__(256) void k_layer1fc(const __hip_bfloat16* __restrict__ h0T,
                                                  const int*   __restrict__ conn1,
                                                  const float* __restrict__ W1,
                                                  const float* __restrict__ b1,
                                                  const float* __restrict__ fc_w,
                                                  float* __restrict__ out) {
    __shared__ float part[4][64];
    const int lane = threadIdx.x & 63;
    const int w    = threadIdx.x >> 6;               // 0..3
    const int n    = blockIdx.x;                     // 0..149
    const int*   __restrict__ cp = conn1 + (n << 6) + (w << 4);
    const float* __restrict__ wp = W1   + (n << 6) + (w << 4);
    float acc = 0.f;
#pragma unroll
    for (int k = 0; k < 16; ++k) {
        acc = fmaf(__bfloat162float(h0T[((size_t)cp[k] << 6) + lane]), wp[k], acc);
    }
    part[w][lane] = acc;
    __syncthreads();
    if (w == 0) {
        const float s = part[0][lane] + part[1][lane] + part[2][lane] + part[3][lane];
        const float h1 = fmaxf(s + b1[n], 0.f);
        atomicAdd(&out[(lane << 1) + 0], h1 * fc_w[n]);        // fc_w[0][n]
        atomicAdd(&out[(lane << 1) + 1], h1 * fc_w[N2 + n]);   // fc_w[1][n]
    }
}

extern "C" void kernel_launch(void* const* d_in, const int* in_sizes, int n_in,
                              void* d_out, int out_size, void* d_ws, size_t ws_size,
                              hipStream_t stream) {
    const float* x     = (const float*)d_in[0];
    const int*   conn0 = (const int*)  d_in[1];
    const int*   conn1 = (const int*)  d_in[2];
    const float* W0    = (const float*)d_in[3];
    const float* b0    = (const float*)d_in[4];
    const float* W1    = (const float*)d_in[5];
    const float* b1    = (const float*)d_in[6];
    const float* fc_w  = (const float*)d_in[7];
    const float* fc_b  = (const float*)d_in[8];
    float* out = (float*)d_out;

    char* ws = (char*)d_ws;
    __hip_bfloat16* xT  = (__hip_bfloat16*)(ws);
    __hip_bfloat16* h0T = (__hip_bfloat16*)(ws + (size_t)N0 * BB * 2);
    unsigned char* used = (unsigned char*)(ws + (size_t)N0 * BB * 2
                                              + (size_t)N1 * BB * 2);

    k_transpose<<<N0 / 64, 256, 0, stream>>>(x, conn1, fc_b, out, xT, used);
    k_layer0<<<N1 / 4, 256, 0, stream>>>(xT, conn0, W0, b0, used, h0T);
    k_layer1fc<<<N2, 256, 0, stream>>>(h0T, conn1, W1, b1, fc_w, out);
}